// Round 4
// baseline (1277.723 us; speedup 1.0000x reference)
//
#include <hip/hip_runtime.h>
#include <hip/hip_bf16.h>

#define IN_DIM 256
#define NHEADS 8
#define HDIM 32
#define BATCH 2
#define NTOK 4096

typedef __hip_bfloat16 bf16;

__device__ __forceinline__ float b2f(bf16 x) { return __bfloat162float(x); }

// ---------------------------------------------------------------------------
// Kernel A: QKV projection with implicit transpose.
//   out[b][n][d] = sum_c X[b][c][n] * W[d][c]
//   X: [B][C][N] fp32 (tgt for Q, src for K/V), W: [256][256] fp32
//   out: [B][N][C] bf16
// grid.x = B*(N/32), grid.y = 3 (Q,K,V); block = 256
// ---------------------------------------------------------------------------
__global__ __launch_bounds__(256) void proj_kernel(
    const float* __restrict__ tgt, const float* __restrict__ src,
    const float* __restrict__ Wq, const float* __restrict__ Wk,
    const float* __restrict__ Wv,
    bf16* __restrict__ Qo, bf16* __restrict__ Ko, bf16* __restrict__ Vo)
{
    const int which = blockIdx.y;
    const float* X = (which == 0) ? tgt : src;
    const float* W = (which == 0) ? Wq : (which == 1 ? Wk : Wv);
    bf16* O        = (which == 0) ? Qo : (which == 1 ? Ko : Vo);

    const int b  = blockIdx.x / (NTOK / 32);
    const int n0 = (blockIdx.x % (NTOK / 32)) * 32;
    const int tid = threadIdx.x;

    __shared__ float Xs[IN_DIM * 32];   // [c][j]

    // 256c x 32j tile as float4: 2048 float4, 8 per thread
    const float* Xbase = X + (size_t)b * IN_DIM * NTOK;
    for (int it = 0; it < 8; ++it) {
        int idx4 = it * 256 + tid;          // float4 index
        int c = idx4 >> 3, j4 = idx4 & 7;   // 8 float4 per 32-wide row
        float4 x = *(const float4*)(Xbase + (size_t)c * NTOK + n0 + j4 * 4);
        *(float4*)&Xs[c * 32 + j4 * 4] = x;
    }
    __syncthreads();

    const int d = tid;                    // each thread owns output column d
    float acc[32];
    #pragma unroll
    for (int j = 0; j < 32; ++j) acc[j] = 0.f;

    const float* Wrow = W + (size_t)d * IN_DIM;
    for (int c0 = 0; c0 < IN_DIM; c0 += 4) {
        float4 w4 = *(const float4*)(Wrow + c0);
        float wv[4] = {w4.x, w4.y, w4.z, w4.w};
        #pragma unroll
        for (int cc = 0; cc < 4; ++cc) {
            const float4* xr = (const float4*)&Xs[(c0 + cc) * 32];
            float w = wv[cc];
            #pragma unroll
            for (int j4 = 0; j4 < 8; ++j4) {
                float4 x = xr[j4];
                acc[j4 * 4 + 0] += x.x * w;
                acc[j4 * 4 + 1] += x.y * w;
                acc[j4 * 4 + 2] += x.z * w;
                acc[j4 * 4 + 3] += x.w * w;
            }
        }
    }
    for (int j = 0; j < 32; ++j)
        O[((size_t)b * NTOK + n0 + j) * IN_DIM + d] = __float2bfloat16(acc[j]);
}

// ---------------------------------------------------------------------------
// Kernel B: flash attention, one thread per query row.
// grid.x = B*NHEADS, grid.y = N/256; block = 256
// Q,K,V: [B][N][C] bf16 (head h = cols h*32..h*32+31); Wt out same layout.
// ---------------------------------------------------------------------------
__global__ __launch_bounds__(256) void attn_kernel(
    const bf16* __restrict__ Q, const bf16* __restrict__ K,
    const bf16* __restrict__ V, bf16* __restrict__ Wt)
{
    const int bh = blockIdx.x;
    const int b = bh / NHEADS, h = bh % NHEADS;
    const int n = blockIdx.y * 256 + threadIdx.x;
    const int tid = threadIdx.x;

    __shared__ float Ks[64 * 32];
    __shared__ float Vs[64 * 32];

    const float scale = 0.17677669529663687f;   // 1/sqrt(32)
    float q[32];
    const bf16* qp = Q + ((size_t)b * NTOK + n) * IN_DIM + h * HDIM;
    #pragma unroll
    for (int c = 0; c < 32; ++c) q[c] = b2f(qp[c]) * scale;

    float m = -1e30f, l = 0.f;
    float acc[32];
    #pragma unroll
    for (int c = 0; c < 32; ++c) acc[c] = 0.f;

    // per-thread staging slot: 8 bf16 = one uint4
    const int sr = tid >> 2;          // row 0..63
    const int sc = (tid & 3) * 8;     // col chunk

    for (int kt = 0; kt < NTOK; kt += 64) {
        __syncthreads();
        {
            size_t g = ((size_t)b * NTOK + kt + sr) * IN_DIM + h * HDIM + sc;
            uint4 kr = *(const uint4*)(K + g);
            uint4 vr = *(const uint4*)(V + g);
            const unsigned int* kw = (const unsigned int*)&kr;
            const unsigned int* vw = (const unsigned int*)&vr;
            #pragma unroll
            for (int t = 0; t < 4; ++t) {
                union { unsigned int i; float f; } lo, hi;
                lo.i = kw[t] << 16; hi.i = kw[t] & 0xffff0000u;
                Ks[sr * 32 + sc + 2 * t]     = lo.f;
                Ks[sr * 32 + sc + 2 * t + 1] = hi.f;
                lo.i = vw[t] << 16; hi.i = vw[t] & 0xffff0000u;
                Vs[sr * 32 + sc + 2 * t]     = lo.f;
                Vs[sr * 32 + sc + 2 * t + 1] = hi.f;
            }
        }
        __syncthreads();

        for (int kk = 0; kk < 64; kk += 4) {
            float s0 = 0.f, s1 = 0.f, s2 = 0.f, s3 = 0.f;
            #pragma unroll
            for (int c = 0; c < 32; ++c) {
                float qc = q[c];
                s0 += qc * Ks[(kk + 0) * 32 + c];
                s1 += qc * Ks[(kk + 1) * 32 + c];
                s2 += qc * Ks[(kk + 2) * 32 + c];
                s3 += qc * Ks[(kk + 3) * 32 + c];
            }
            float mn = fmaxf(fmaxf(s0, s1), fmaxf(s2, s3));
            mn = fmaxf(m, mn);
            float corr = __expf(m - mn);
            m = mn;
            l *= corr;
            #pragma unroll
            for (int c = 0; c < 32; ++c) acc[c] *= corr;
            float p0 = __expf(s0 - m), p1 = __expf(s1 - m);
            float p2 = __expf(s2 - m), p3 = __expf(s3 - m);
            l += p0 + p1 + p2 + p3;
            #pragma unroll
            for (int c = 0; c < 32; ++c) {
                acc[c] += p0 * Vs[(kk + 0) * 32 + c] + p1 * Vs[(kk + 1) * 32 + c]
                        + p2 * Vs[(kk + 2) * 32 + c] + p3 * Vs[(kk + 3) * 32 + c];
            }
        }
    }

    const float inv = 1.f / l;
    bf16* op = Wt + ((size_t)b * NTOK + n) * IN_DIM + h * HDIM;
    #pragma unroll
    for (int c = 0; c < 32; ++c) op[c] = __float2bfloat16(acc[c] * inv);
}

// ---------------------------------------------------------------------------
// Kernel C: out[b][n][d] = sum_c (Wt[b][n][c] + tgt[b][c][n]) * Wo[d][c]
// out: fp32. grid.x = B*(N/32); block = 256
// ---------------------------------------------------------------------------
__global__ __launch_bounds__(256) void out_kernel(
    const bf16* __restrict__ Wt, const float* __restrict__ tgt,
    const float* __restrict__ Wo, float* __restrict__ out)
{
    const int b  = blockIdx.x / (NTOK / 32);
    const int n0 = (blockIdx.x % (NTOK / 32)) * 32;
    const int tid = threadIdx.x;

    __shared__ float Xs[IN_DIM * 32];   // [c][j]

    // phase 1: tgt (coalesced: consecutive lanes -> consecutive j)
    const float* Tbase = tgt + (size_t)b * IN_DIM * NTOK;
    for (int it = 0; it < 8; ++it) {
        int idx4 = it * 256 + tid;
        int c = idx4 >> 3, j4 = idx4 & 7;
        float4 x = *(const float4*)(Tbase + (size_t)c * NTOK + n0 + j4 * 4);
        *(float4*)&Xs[c * 32 + j4 * 4] = x;
    }
    __syncthreads();
    // phase 2: add Wt
    for (int j = 0; j < 32; ++j) {
        float wv = b2f(Wt[((size_t)b * NTOK + n0 + j) * IN_DIM + tid]);
        Xs[tid * 32 + j] += wv;
    }
    __syncthreads();

    const int d = tid;
    float acc[32];
    #pragma unroll
    for (int j = 0; j < 32; ++j) acc[j] = 0.f;

    const float* Wrow = Wo + (size_t)d * IN_DIM;
    for (int c0 = 0; c0 < IN_DIM; c0 += 4) {
        float4 w4 = *(const float4*)(Wrow + c0);
        float wv[4] = {w4.x, w4.y, w4.z, w4.w};
        #pragma unroll
        for (int cc = 0; cc < 4; ++cc) {
            const float4* xr = (const float4*)&Xs[(c0 + cc) * 32];
            float w = wv[cc];
            #pragma unroll
            for (int j4 = 0; j4 < 8; ++j4) {
                float4 x = xr[j4];
                acc[j4 * 4 + 0] += x.x * w;
                acc[j4 * 4 + 1] += x.y * w;
                acc[j4 * 4 + 2] += x.z * w;
                acc[j4 * 4 + 3] += x.w * w;
            }
        }
    }
    for (int j = 0; j < 32; ++j)
        out[((size_t)b * NTOK + n0 + j) * IN_DIM + d] = acc[j];
}

// ---------------------------------------------------------------------------
extern "C" void kernel_launch(void* const* d_in, const int* in_sizes, int n_in,
                              void* d_out, int out_size, void* d_ws, size_t ws_size,
                              hipStream_t stream) {
    const float* tgt = (const float*)d_in[0];
    const float* src = (const float*)d_in[1];
    const float* Wq  = (const float*)d_in[2];
    const float* Wk  = (const float*)d_in[3];
    const float* Wv  = (const float*)d_in[4];
    const float* Wo  = (const float*)d_in[5];
    float* out = (float*)d_out;

    const size_t SZ = (size_t)BATCH * NTOK * IN_DIM * sizeof(bf16);  // 4 MiB
    char* w = (char*)d_ws;
    bf16* Qb = (bf16*)(w);
    bf16* Kb = (bf16*)(w + SZ);
    bf16* Vb = (bf16*)(w + 2 * SZ);
    bf16* Wt = (bf16*)(w + 3 * SZ);

    dim3 gA(BATCH * (NTOK / 32), 3);
    proj_kernel<<<gA, 256, 0, stream>>>(tgt, src, Wq, Wk, Wv, Qb, Kb, Vb);

    dim3 gB(BATCH * NHEADS, NTOK / 256);
    attn_kernel<<<gB, 256, 0, stream>>>(Qb, Kb, Vb, Wt);

    out_kernel<<<BATCH * (NTOK / 32), 256, 0, stream>>>(Wt, tgt, Wo, out);
}

// Round 5
// 315.396 us; speedup vs baseline: 4.0512x; 4.0512x over previous
//
#include <hip/hip_runtime.h>
#include <hip/hip_bf16.h>

#define IN_DIM 256
#define NHEADS 8
#define HDIM 32
#define BATCH 2
#define NTOK 4096

typedef __hip_bfloat16 bf16;
typedef __attribute__((ext_vector_type(8))) short bf16x8;
typedef __attribute__((ext_vector_type(4))) float f32x4;

__device__ __forceinline__ float b2f(bf16 x) { return __bfloat162float(x); }

// ---------------------------------------------------------------------------
// Kernel A: QKV projection with implicit transpose.
//   out[b][n][d] = sum_c X[b][c][n] * W[d][c]
// Q is pre-scaled by 1/sqrt(32) * log2(e) so attention can use exp2.
// grid.x = B*(N/32), grid.y = 3 (Q,K,V); block = 256
// ---------------------------------------------------------------------------
__global__ __launch_bounds__(256) void proj_kernel(
    const float* __restrict__ tgt, const float* __restrict__ src,
    const float* __restrict__ Wq, const float* __restrict__ Wk,
    const float* __restrict__ Wv,
    bf16* __restrict__ Qo, bf16* __restrict__ Ko, bf16* __restrict__ Vo)
{
    const int which = blockIdx.y;
    const float* X = (which == 0) ? tgt : src;
    const float* W = (which == 0) ? Wq : (which == 1 ? Wk : Wv);
    bf16* O        = (which == 0) ? Qo : (which == 1 ? Ko : Vo);
    const float oscale = (which == 0) ? (0.17677669529663687f * 1.4426950408889634f) : 1.0f;

    const int b  = blockIdx.x / (NTOK / 32);
    const int n0 = (blockIdx.x % (NTOK / 32)) * 32;
    const int tid = threadIdx.x;

    __shared__ float Xs[IN_DIM * 32];   // [c][j]

    const float* Xbase = X + (size_t)b * IN_DIM * NTOK;
    for (int it = 0; it < 8; ++it) {
        int idx4 = it * 256 + tid;          // float4 index
        int c = idx4 >> 3, j4 = idx4 & 7;
        float4 x = *(const float4*)(Xbase + (size_t)c * NTOK + n0 + j4 * 4);
        *(float4*)&Xs[c * 32 + j4 * 4] = x;
    }
    __syncthreads();

    const int d = tid;
    float acc[32];
    #pragma unroll
    for (int j = 0; j < 32; ++j) acc[j] = 0.f;

    const float* Wrow = W + (size_t)d * IN_DIM;
    for (int c0 = 0; c0 < IN_DIM; c0 += 4) {
        float4 w4 = *(const float4*)(Wrow + c0);
        float wv[4] = {w4.x, w4.y, w4.z, w4.w};
        #pragma unroll
        for (int cc = 0; cc < 4; ++cc) {
            const float4* xr = (const float4*)&Xs[(c0 + cc) * 32];
            float w = wv[cc];
            #pragma unroll
            for (int j4 = 0; j4 < 8; ++j4) {
                float4 x = xr[j4];
                acc[j4 * 4 + 0] += x.x * w;
                acc[j4 * 4 + 1] += x.y * w;
                acc[j4 * 4 + 2] += x.z * w;
                acc[j4 * 4 + 3] += x.w * w;
            }
        }
    }
    for (int j = 0; j < 32; ++j)
        O[((size_t)b * NTOK + n0 + j) * IN_DIM + d] = __float2bfloat16(acc[j] * oscale);
}

// ---------------------------------------------------------------------------
// Kernel B: MFMA flash attention.
// grid.x = (B*NHEADS)*64; block = 256 (4 waves, each owns 16 q-rows).
// Q pre-scaled by scale*log2e.  All MFMA products load both operands with the
// same contiguous-8 per-lane k-pattern (layout-agnostic); C/D layout
// (row=(lane>>4)*4+reg, col=lane&15) is the HW-verified one.
// ---------------------------------------------------------------------------
__global__ __launch_bounds__(256) void attn_mfma_kernel(
    const bf16* __restrict__ Q, const bf16* __restrict__ K,
    const bf16* __restrict__ V, bf16* __restrict__ Wt)
{
    const int bh = blockIdx.x >> 6;          // 0..15
    const int b  = bh >> 3, h = bh & 7;
    const int q0 = (blockIdx.x & 63) * 64;
    const int tid  = threadIdx.x;
    const int wave = tid >> 6;
    const int lane = tid & 63;
    const int lg = lane >> 4, lc = lane & 15;

    __shared__ __align__(16) bf16 Klds[64 * 40];      // [kcol][d], stride 40
    __shared__ __align__(16) bf16 Vt[32 * 72];        // [d][k],   stride 72
    __shared__ __align__(16) bf16 Plds[4][16 * 72];   // per-wave [q][k], stride 72

    // Q fragment (A): row = lc, k(d) = 8*lg + e
    const bf16x8 qf = *(const bf16x8*)(Q + ((size_t)b * NTOK + q0 + wave * 16 + lc) * IN_DIM
                                         + h * HDIM + lg * 8);

    f32x4 o0 = {0.f, 0.f, 0.f, 0.f};   // d = lc
    f32x4 o1 = {0.f, 0.f, 0.f, 0.f};   // d = 16 + lc
    float m[4] = {-1e30f, -1e30f, -1e30f, -1e30f};
    float l[4] = {0.f, 0.f, 0.f, 0.f};

    const int srow = tid >> 2;          // 0..63 (kv row)
    const int sd   = (tid & 3) * 8;     // d chunk

    for (int kt = 0; kt < NTOK; kt += 64) {
        __syncthreads();
        {
            const size_t g = ((size_t)b * NTOK + kt + srow) * IN_DIM + h * HDIM + sd;
            bf16x8 kv = *(const bf16x8*)(K + g);
            bf16x8 vv = *(const bf16x8*)(V + g);
            *(bf16x8*)&Klds[srow * 40 + sd] = kv;
            #pragma unroll
            for (int i = 0; i < 8; ++i)                     // transpose V into Vt
                Vt[(sd + i) * 72 + srow] = ((const bf16*)&vv)[i];
        }
        __syncthreads();

        // ---- QK^T: 4 16x16 score tiles
        f32x4 s[4];
        #pragma unroll
        for (int t = 0; t < 4; ++t) {
            bf16x8 kf = *(const bf16x8*)&Klds[(t * 16 + lc) * 40 + lg * 8];
            f32x4 z = {0.f, 0.f, 0.f, 0.f};
            s[t] = __builtin_amdgcn_mfma_f32_16x16x32_bf16(qf, kf, z, 0, 0, 0);
        }

        // ---- online softmax (base 2); write P to this wave's LDS
        #pragma unroll
        for (int r = 0; r < 4; ++r) {
            float mx = fmaxf(fmaxf(s[0][r], s[1][r]), fmaxf(s[2][r], s[3][r]));
            mx = fmaxf(mx, __shfl_xor(mx, 1));
            mx = fmaxf(mx, __shfl_xor(mx, 2));
            mx = fmaxf(mx, __shfl_xor(mx, 4));
            mx = fmaxf(mx, __shfl_xor(mx, 8));
            float mn = fmaxf(m[r], mx);
            float corr = exp2f(m[r] - mn);
            m[r] = mn;
            float ps = 0.f;
            #pragma unroll
            for (int t = 0; t < 4; ++t) {
                float p = exp2f(s[t][r] - mn);
                ps += p;
                Plds[wave][(lg * 4 + r) * 72 + t * 16 + lc] = __float2bfloat16(p);
            }
            ps += __shfl_xor(ps, 1);
            ps += __shfl_xor(ps, 2);
            ps += __shfl_xor(ps, 4);
            ps += __shfl_xor(ps, 8);
            l[r] = l[r] * corr + ps;
            o0[r] *= corr;
            o1[r] *= corr;
        }

        // ---- PV: O[16q][32d] += P[16q][64k] * V[64k][32d]
        #pragma unroll
        for (int kc = 0; kc < 2; ++kc) {
            bf16x8 pf = *(const bf16x8*)&Plds[wave][lc * 72 + kc * 32 + lg * 8];
            bf16x8 v0 = *(const bf16x8*)&Vt[lc * 72 + kc * 32 + lg * 8];
            bf16x8 v1 = *(const bf16x8*)&Vt[(16 + lc) * 72 + kc * 32 + lg * 8];
            o0 = __builtin_amdgcn_mfma_f32_16x16x32_bf16(pf, v0, o0, 0, 0, 0);
            o1 = __builtin_amdgcn_mfma_f32_16x16x32_bf16(pf, v1, o1, 0, 0, 0);
        }
    }

    bf16* op = Wt + ((size_t)b * NTOK + q0 + wave * 16 + lg * 4) * IN_DIM + h * HDIM + lc;
    #pragma unroll
    for (int r = 0; r < 4; ++r) {
        float inv = 1.f / l[r];
        op[(size_t)r * IN_DIM]      = __float2bfloat16(o0[r] * inv);
        op[(size_t)r * IN_DIM + 16] = __float2bfloat16(o1[r] * inv);
    }
}

// ---------------------------------------------------------------------------
// Kernel C: out[b][n][d] = sum_c (Wt[b][n][c] + tgt[b][c][n]) * Wo[d][c]
// out: fp32. grid.x = B*(N/32); block = 256
// ---------------------------------------------------------------------------
__global__ __launch_bounds__(256) void out_kernel(
    const bf16* __restrict__ Wt, const float* __restrict__ tgt,
    const float* __restrict__ Wo, float* __restrict__ out)
{
    const int b  = blockIdx.x / (NTOK / 32);
    const int n0 = (blockIdx.x % (NTOK / 32)) * 32;
    const int tid = threadIdx.x;

    __shared__ float Xs[IN_DIM * 32];   // [c][j]

    const float* Tbase = tgt + (size_t)b * IN_DIM * NTOK;
    for (int it = 0; it < 8; ++it) {
        int idx4 = it * 256 + tid;
        int c = idx4 >> 3, j4 = idx4 & 7;
        float4 x = *(const float4*)(Tbase + (size_t)c * NTOK + n0 + j4 * 4);
        *(float4*)&Xs[c * 32 + j4 * 4] = x;
    }
    __syncthreads();
    for (int j = 0; j < 32; ++j) {
        float wv = b2f(Wt[((size_t)b * NTOK + n0 + j) * IN_DIM + tid]);
        Xs[tid * 32 + j] += wv;
    }
    __syncthreads();

    const int d = tid;
    float acc[32];
    #pragma unroll
    for (int j = 0; j < 32; ++j) acc[j] = 0.f;

    const float* Wrow = Wo + (size_t)d * IN_DIM;
    for (int c0 = 0; c0 < IN_DIM; c0 += 4) {
        float4 w4 = *(const float4*)(Wrow + c0);
        float wv[4] = {w4.x, w4.y, w4.z, w4.w};
        #pragma unroll
        for (int cc = 0; cc < 4; ++cc) {
            const float4* xr = (const float4*)&Xs[(c0 + cc) * 32];
            float w = wv[cc];
            #pragma unroll
            for (int j4 = 0; j4 < 8; ++j4) {
                float4 x = xr[j4];
                acc[j4 * 4 + 0] += x.x * w;
                acc[j4 * 4 + 1] += x.y * w;
                acc[j4 * 4 + 2] += x.z * w;
                acc[j4 * 4 + 3] += x.w * w;
            }
        }
    }
    for (int j = 0; j < 32; ++j)
        out[((size_t)b * NTOK + n0 + j) * IN_DIM + d] = acc[j];
}

// ---------------------------------------------------------------------------
extern "C" void kernel_launch(void* const* d_in, const int* in_sizes, int n_in,
                              void* d_out, int out_size, void* d_ws, size_t ws_size,
                              hipStream_t stream) {
    const float* tgt = (const float*)d_in[0];
    const float* src = (const float*)d_in[1];
    const float* Wq  = (const float*)d_in[2];
    const float* Wk  = (const float*)d_in[3];
    const float* Wv  = (const float*)d_in[4];
    const float* Wo  = (const float*)d_in[5];
    float* out = (float*)d_out;

    const size_t SZ = (size_t)BATCH * NTOK * IN_DIM * sizeof(bf16);  // 4 MiB
    char* w = (char*)d_ws;
    bf16* Qb = (bf16*)(w);
    bf16* Kb = (bf16*)(w + SZ);
    bf16* Vb = (bf16*)(w + 2 * SZ);
    bf16* Wt = (bf16*)(w + 3 * SZ);

    dim3 gA(BATCH * (NTOK / 32), 3);
    proj_kernel<<<gA, 256, 0, stream>>>(tgt, src, Wq, Wk, Wv, Qb, Kb, Vb);

    attn_mfma_kernel<<<BATCH * NHEADS * 64, 256, 0, stream>>>(Qb, Kb, Vb, Wt);

    out_kernel<<<BATCH * (NTOK / 32), 256, 0, stream>>>(Wt, tgt, Wo, out);
}

// Round 6
// 224.087 us; speedup vs baseline: 5.7019x; 1.4075x over previous
//
#include <hip/hip_runtime.h>
#include <hip/hip_bf16.h>

#define IN_DIM 256
#define NHEADS 8
#define HDIM 32
#define BATCH 2
#define NTOK 4096

typedef __hip_bfloat16 bf16;
typedef __attribute__((ext_vector_type(8))) short bf16x8;
typedef __attribute__((ext_vector_type(4))) short bf16x4;
typedef __attribute__((ext_vector_type(4))) float f32x4;

__device__ __forceinline__ float b2f(bf16 x) { return __bfloat162float(x); }
__device__ __forceinline__ unsigned f2bfbits(float x) {
    bf16 h = __float2bfloat16(x);
    unsigned short us;
    __builtin_memcpy(&us, &h, 2);
    return us;
}

// ---------------------------------------------------------------------------
// Kernel A: QKV projection with implicit transpose.
//   out[b][n][d] = sum_c X[b][c][n] * W[d][c]
// Q is pre-scaled by 1/sqrt(32) * log2(e) so attention can use exp2.
// grid.x = B*(N/32), grid.y = 3 (Q,K,V); block = 256
// ---------------------------------------------------------------------------
__global__ __launch_bounds__(256) void proj_kernel(
    const float* __restrict__ tgt, const float* __restrict__ src,
    const float* __restrict__ Wq, const float* __restrict__ Wk,
    const float* __restrict__ Wv,
    bf16* __restrict__ Qo, bf16* __restrict__ Ko, bf16* __restrict__ Vo)
{
    const int which = blockIdx.y;
    const float* X = (which == 0) ? tgt : src;
    const float* W = (which == 0) ? Wq : (which == 1 ? Wk : Wv);
    bf16* O        = (which == 0) ? Qo : (which == 1 ? Ko : Vo);
    const float oscale = (which == 0) ? (0.17677669529663687f * 1.4426950408889634f) : 1.0f;

    const int b  = blockIdx.x / (NTOK / 32);
    const int n0 = (blockIdx.x % (NTOK / 32)) * 32;
    const int tid = threadIdx.x;

    __shared__ float Xs[IN_DIM * 32];   // [c][j]

    const float* Xbase = X + (size_t)b * IN_DIM * NTOK;
    for (int it = 0; it < 8; ++it) {
        int idx4 = it * 256 + tid;          // float4 index
        int c = idx4 >> 3, j4 = idx4 & 7;
        float4 x = *(const float4*)(Xbase + (size_t)c * NTOK + n0 + j4 * 4);
        *(float4*)&Xs[c * 32 + j4 * 4] = x;
    }
    __syncthreads();

    const int d = tid;
    float acc[32];
    #pragma unroll
    for (int j = 0; j < 32; ++j) acc[j] = 0.f;

    const float* Wrow = W + (size_t)d * IN_DIM;
    for (int c0 = 0; c0 < IN_DIM; c0 += 4) {
        float4 w4 = *(const float4*)(Wrow + c0);
        float wv[4] = {w4.x, w4.y, w4.z, w4.w};
        #pragma unroll
        for (int cc = 0; cc < 4; ++cc) {
            const float4* xr = (const float4*)&Xs[(c0 + cc) * 32];
            float w = wv[cc];
            #pragma unroll
            for (int j4 = 0; j4 < 8; ++j4) {
                float4 x = xr[j4];
                acc[j4 * 4 + 0] += x.x * w;
                acc[j4 * 4 + 1] += x.y * w;
                acc[j4 * 4 + 2] += x.z * w;
                acc[j4 * 4 + 3] += x.w * w;
            }
        }
    }
    for (int j = 0; j < 32; ++j)
        O[((size_t)b * NTOK + n0 + j) * IN_DIM + d] = __float2bfloat16(acc[j] * oscale);
}

// ---------------------------------------------------------------------------
// Kernel B: MFMA flash attention, swapped-QK^T softmax (in-lane reductions).
// grid.x = (B*NHEADS)*64; block = 256 (4 waves x 16 q-rows).
//   S^T = mfma(kf, qf): lane (lg,lc) holds S[k = t*16+lg*4+r][q = lc].
//   Row reductions are in-lane trees + 2 shfl_xor (16,32).
//   P packed to bf16x4 -> ds_write_b64 into per-wave Plds[q][k] (stride 72).
//   V transposed in LDS, stride 68 (spreads sd-group banks; 8B-aligned reads).
//   Defer-max: rescale only when !__all(pmax - m <= 8).
// ---------------------------------------------------------------------------
__global__ __launch_bounds__(256) void attn_mfma_kernel(
    const bf16* __restrict__ Q, const bf16* __restrict__ K,
    const bf16* __restrict__ V, bf16* __restrict__ Wt)
{
    const int bh = blockIdx.x >> 6;          // 0..15
    const int b  = bh >> 3, h = bh & 7;
    const int q0 = (blockIdx.x & 63) * 64;
    const int tid  = threadIdx.x;
    const int wave = tid >> 6;
    const int lane = tid & 63;
    const int lg = lane >> 4, lc = lane & 15;

    __shared__ __align__(16) bf16 Klds[64 * 40];      // [k][d]  stride 40
    __shared__ __align__(16) bf16 Vt[32 * 68];        // [d][k]  stride 68
    __shared__ __align__(16) bf16 Plds[4][16 * 72];   // per-wave [q][k] stride 72
    __shared__ float redLds[4][16];                   // per-wave corr / final l

    // Q fragment (B-operand): row=q=lc, k-slice = lg*8..lg*8+7
    const bf16x8 qf = *(const bf16x8*)(Q + ((size_t)b * NTOK + q0 + wave * 16 + lc) * IN_DIM
                                         + h * HDIM + lg * 8);

    f32x4 o0 = {0.f, 0.f, 0.f, 0.f};   // D rows q=lg*4+r, col d=lc
    f32x4 o1 = {0.f, 0.f, 0.f, 0.f};   // col d=16+lc
    float m = -1e30f, l = 0.f;         // running stats for q = lc

    const int srow = tid >> 2;          // kv row 0..63
    const int sd   = (tid & 3) * 8;     // d chunk
    const bf16* Kg = K + ((size_t)b * NTOK + srow) * IN_DIM + h * HDIM + sd;
    const bf16* Vg = V + ((size_t)b * NTOK + srow) * IN_DIM + h * HDIM + sd;

    for (int kt = 0; kt < NTOK; kt += 64) {
        bf16x8 kv = *(const bf16x8*)(Kg + (size_t)kt * IN_DIM);
        bf16x8 vv = *(const bf16x8*)(Vg + (size_t)kt * IN_DIM);
        __syncthreads();
        *(bf16x8*)&Klds[srow * 40 + sd] = kv;
        #pragma unroll
        for (int i = 0; i < 8; ++i)
            Vt[(sd + i) * 68 + srow] = ((const bf16*)&vv)[i];
        __syncthreads();

        // ---- S^T tiles: A = K rows, B = Q rows
        f32x4 s[4];
        #pragma unroll
        for (int t = 0; t < 4; ++t) {
            bf16x8 kf = *(const bf16x8*)&Klds[(t * 16 + lc) * 40 + lg * 8];
            f32x4 z = {0.f, 0.f, 0.f, 0.f};
            s[t] = __builtin_amdgcn_mfma_f32_16x16x32_bf16(kf, qf, z, 0, 0, 0);
        }

        // ---- in-lane softmax for q = lc (16 scores per lane)
        float sv[16];
        #pragma unroll
        for (int t = 0; t < 4; ++t)
            #pragma unroll
            for (int r = 0; r < 4; ++r) sv[t * 4 + r] = s[t][r];

        float mt[8];
        #pragma unroll
        for (int i = 0; i < 8; ++i) mt[i] = fmaxf(sv[i], sv[i + 8]);
        #pragma unroll
        for (int w = 4; w >= 1; w >>= 1)
            #pragma unroll
            for (int i = 0; i < w; ++i) mt[i] = fmaxf(mt[i], mt[i + w]);
        float pmax = mt[0];
        pmax = fmaxf(pmax, __shfl_xor(pmax, 16));
        pmax = fmaxf(pmax, __shfl_xor(pmax, 32));

        const bool resc = !__all(pmax - m <= 8.0f);
        float corr = 1.f;
        if (resc) {
            float mn = fmaxf(m, pmax);
            corr = exp2f(m - mn);
            m = mn;
            redLds[wave][lc] = corr;
        }

        float p[16];
        #pragma unroll
        for (int i = 0; i < 16; ++i) p[i] = exp2f(sv[i] - m);

        float st[8];
        #pragma unroll
        for (int i = 0; i < 8; ++i) st[i] = p[i] + p[i + 8];
        #pragma unroll
        for (int w = 4; w >= 1; w >>= 1)
            #pragma unroll
            for (int i = 0; i < w; ++i) st[i] += st[i + w];
        float ps = st[0];
        ps += __shfl_xor(ps, 16);
        ps += __shfl_xor(ps, 32);
        l = l * corr + ps;

        // ---- pack P (kv = t*16+lg*4+r are consecutive in r) -> b64 writes
        #pragma unroll
        for (int t = 0; t < 4; ++t) {
            uint2 pk;
            pk.x = f2bfbits(p[t * 4 + 0]) | (f2bfbits(p[t * 4 + 1]) << 16);
            pk.y = f2bfbits(p[t * 4 + 2]) | (f2bfbits(p[t * 4 + 3]) << 16);
            *(uint2*)&Plds[wave][lc * 72 + t * 16 + lg * 4] = pk;
        }

        // ---- rescale accumulator (rare): corr for q = lg*4+r
        if (resc) {
            float c0 = redLds[wave][lg * 4 + 0];
            float c1 = redLds[wave][lg * 4 + 1];
            float c2 = redLds[wave][lg * 4 + 2];
            float c3 = redLds[wave][lg * 4 + 3];
            o0[0] *= c0; o0[1] *= c1; o0[2] *= c2; o0[3] *= c3;
            o1[0] *= c0; o1[1] *= c1; o1[2] *= c2; o1[3] *= c3;
        }

        // ---- PV: O[q][d] += P[q][kv] * Vt[d][kv]
        #pragma unroll
        for (int kc = 0; kc < 2; ++kc) {
            bf16x8 pf = *(const bf16x8*)&Plds[wave][lc * 72 + kc * 32 + lg * 8];
            union { bf16x8 v8; bf16x4 h[2]; } u0, u1;
            u0.h[0] = *(const bf16x4*)&Vt[lc * 68 + kc * 32 + lg * 8];
            u0.h[1] = *(const bf16x4*)&Vt[lc * 68 + kc * 32 + lg * 8 + 4];
            u1.h[0] = *(const bf16x4*)&Vt[(16 + lc) * 68 + kc * 32 + lg * 8];
            u1.h[1] = *(const bf16x4*)&Vt[(16 + lc) * 68 + kc * 32 + lg * 8 + 4];
            o0 = __builtin_amdgcn_mfma_f32_16x16x32_bf16(pf, u0.v8, o0, 0, 0, 0);
            o1 = __builtin_amdgcn_mfma_f32_16x16x32_bf16(pf, u1.v8, o1, 0, 0, 0);
        }
    }

    // redistribute l (computed for q=lc) to the D-layout rows (q=lg*4+r)
    redLds[wave][lc] = l;
    bf16* op = Wt + ((size_t)b * NTOK + q0 + wave * 16 + lg * 4) * IN_DIM + h * HDIM + lc;
    #pragma unroll
    for (int r = 0; r < 4; ++r) {
        float inv = 1.f / redLds[wave][lg * 4 + r];
        op[(size_t)r * IN_DIM]      = __float2bfloat16(o0[r] * inv);
        op[(size_t)r * IN_DIM + 16] = __float2bfloat16(o1[r] * inv);
    }
}

// ---------------------------------------------------------------------------
// Kernel C: out[b][n][d] = sum_c (Wt[b][n][c] + tgt[b][c][n]) * Wo[d][c]
// Wt add folded into the register-side staging (no 32-way LDS conflict pass).
// out: fp32. grid.x = B*(N/32); block = 256
// ---------------------------------------------------------------------------
__global__ __launch_bounds__(256) void out_kernel(
    const bf16* __restrict__ Wt, const float* __restrict__ tgt,
    const float* __restrict__ Wo, float* __restrict__ out)
{
    const int b  = blockIdx.x / (NTOK / 32);
    const int n0 = (blockIdx.x % (NTOK / 32)) * 32;
    const int tid = threadIdx.x;

    __shared__ float Xs[IN_DIM * 32];   // [c][j]

    const float* Tbase = tgt + (size_t)b * IN_DIM * NTOK;
    for (int it = 0; it < 8; ++it) {
        int idx4 = it * 256 + tid;
        int c = idx4 >> 3, j4 = idx4 & 7;
        float4 x = *(const float4*)(Tbase + (size_t)c * NTOK + n0 + j4 * 4);
        const bf16* wp = Wt + ((size_t)b * NTOK + n0 + j4 * 4) * IN_DIM + c;
        x.x += b2f(wp[0]);
        x.y += b2f(wp[IN_DIM]);
        x.z += b2f(wp[2 * IN_DIM]);
        x.w += b2f(wp[3 * IN_DIM]);
        *(float4*)&Xs[c * 32 + j4 * 4] = x;
    }
    __syncthreads();

    const int d = tid;
    float acc[32];
    #pragma unroll
    for (int j = 0; j < 32; ++j) acc[j] = 0.f;

    const float* Wrow = Wo + (size_t)d * IN_DIM;
    for (int c0 = 0; c0 < IN_DIM; c0 += 4) {
        float4 w4 = *(const float4*)(Wrow + c0);
        float wv[4] = {w4.x, w4.y, w4.z, w4.w};
        #pragma unroll
        for (int cc = 0; cc < 4; ++cc) {
            const float4* xr = (const float4*)&Xs[(c0 + cc) * 32];
            float w = wv[cc];
            #pragma unroll
            for (int j4 = 0; j4 < 8; ++j4) {
                float4 x = xr[j4];
                acc[j4 * 4 + 0] += x.x * w;
                acc[j4 * 4 + 1] += x.y * w;
                acc[j4 * 4 + 2] += x.z * w;
                acc[j4 * 4 + 3] += x.w * w;
            }
        }
    }
    for (int j = 0; j < 32; ++j)
        out[((size_t)b * NTOK + n0 + j) * IN_DIM + d] = acc[j];
}

// ---------------------------------------------------------------------------
extern "C" void kernel_launch(void* const* d_in, const int* in_sizes, int n_in,
                              void* d_out, int out_size, void* d_ws, size_t ws_size,
                              hipStream_t stream) {
    const float* tgt = (const float*)d_in[0];
    const float* src = (const float*)d_in[1];
    const float* Wq  = (const float*)d_in[2];
    const float* Wk  = (const float*)d_in[3];
    const float* Wv  = (const float*)d_in[4];
    const float* Wo  = (const float*)d_in[5];
    float* out = (float*)d_out;

    const size_t SZ = (size_t)BATCH * NTOK * IN_DIM * sizeof(bf16);  // 4 MiB
    char* w = (char*)d_ws;
    bf16* Qb = (bf16*)(w);
    bf16* Kb = (bf16*)(w + SZ);
    bf16* Vb = (bf16*)(w + 2 * SZ);
    bf16* Wt = (bf16*)(w + 3 * SZ);

    dim3 gA(BATCH * (NTOK / 32), 3);
    proj_kernel<<<gA, 256, 0, stream>>>(tgt, src, Wq, Wk, Wv, Qb, Kb, Vb);

    attn_mfma_kernel<<<BATCH * NHEADS * 64, 256, 0, stream>>>(Qb, Kb, Vb, Wt);

    out_kernel<<<BATCH * (NTOK / 32), 256, 0, stream>>>(Wt, tgt, Wo, out);
}